// Round 2
// baseline (531.072 us; speedup 1.0000x reference)
//
#include <hip/hip_runtime.h>
#include <hip/hip_fp16.h>
#include <stdint.h>

// Problem constants
#define Bb 8
#define Tt 4096
#define Cc 512
#define Hh 512
#define Mm (Bb*Tt)      // 32768
#define Nn (3*Hh)       // 1536
#define Kk (2*Cc)       // 1024
#define NC 64           // chunks per batch for the scan
#define LC (Tt/NC)      // 64 steps per chunk
#define XBS (Tt*Cc + Cc) // per-batch padded x stride (elems) = 2097664

typedef _Float16 half8 __attribute__((ext_vector_type(8)));
typedef _Float16 half4 __attribute__((ext_vector_type(4)));
typedef float  floatx4 __attribute__((ext_vector_type(4)));

__device__ __forceinline__ float fsigmoid(float x) {
    return 1.0f / (1.0f + __expf(-x));
}
__device__ __forceinline__ float ftanh(float x) {
    return 2.0f / (1.0f + __expf(-2.0f * x)) - 1.0f;
}

// ---- x fp32 -> fp16 with 512-elem zero pad at front of each batch ----
__global__ __launch_bounds__(256) void cvt_x(const float* __restrict__ x,
                                             _Float16* __restrict__ xh) {
    long i4 = ((long)blockIdx.x * 256 + threadIdx.x) * 4;   // [0, XBS)
    int b = blockIdx.y;
    if (i4 >= XBS) return;
    half4 v;
    if (i4 >= Cc) {
        floatx4 xx = *(const floatx4*)&x[(long)b * (Tt*Cc) + i4 - Cc];
        v[0] = (_Float16)xx[0]; v[1] = (_Float16)xx[1];
        v[2] = (_Float16)xx[2]; v[3] = (_Float16)xx[3];
    } else {
        v[0] = v[1] = v[2] = v[3] = (_Float16)0.0f;
    }
    *(half4*)&xh[(long)b * XBS + i4] = v;
}

// ---- build Bt[n][kk] = kernel_{n/512}[kk/512][kk%512][n%512] as fp16 ----
__global__ __launch_bounds__(256) void cvt_w(const float* __restrict__ zk,
                                             const float* __restrict__ fk,
                                             const float* __restrict__ ok,
                                             _Float16* __restrict__ bt) {
    int idx = blockIdx.x * 256 + threadIdx.x; // < 1536*1024
    int n  = idx >> 10;
    int kk = idx & 1023;
    int which = n >> 9;
    int h = n & 511;
    int kw = kk >> 9;
    int c = kk & 511;
    const float* src = (which == 0) ? zk : ((which == 1) ? fk : ok);
    bt[idx] = (_Float16)src[kw * (Cc*Hh) + c * Hh + h];
}

// ---- MFMA fp16 GEMM, register-direct (no LDS, no barriers) ----
// Y[m][n] = act_gate(A[m][:] @ Bt[n][:] + bias[n]), stored fp16.
// Each wave owns a 64x64 tile; fragments loaded straight from global.
__global__ __launch_bounds__(256, 3) void gemm_qrnn(const _Float16* __restrict__ xh,
                                                    const _Float16* __restrict__ bt,
                                                    const float* __restrict__ zb,
                                                    const float* __restrict__ fb,
                                                    const float* __restrict__ ob,
                                                    _Float16* __restrict__ yh) {
    const int tid  = threadIdx.x;
    const int lane = tid & 63;
    const int w    = tid >> 6;          // wave 0..3
    const int m0   = blockIdx.x * 128;
    const int n0   = blockIdx.y * 128;
    const int wm   = (w & 1) * 64;      // wave m-offset (waves 0,2 share A rows? no: 0&1 differ)
    const int wn   = (w >> 1) * 64;     // wave n-offset
    const int q    = lane >> 4;         // lane quad -> k-subgroup (k = q*8..q*8+7)
    const int l15  = lane & 15;

    // Fragment base pointers. A uses the causal-pad trick:
    // A[m][k] = xh[(m + (m>>12))*512 + k], contiguous over k in [0,1024).
    const _Float16* ap[4];
    const _Float16* bp[4];
#pragma unroll
    for (int mi = 0; mi < 4; ++mi) {
        int mg = m0 + wm + mi * 16 + l15;
        ap[mi] = xh + (((long)(mg + (mg >> 12))) << 9) + q * 8;
    }
#pragma unroll
    for (int ni = 0; ni < 4; ++ni) {
        int ng = n0 + wn + ni * 16 + l15;
        bp[ni] = bt + (((long)ng) << 10) + q * 8;
    }

    floatx4 acc[4][4] = {};
    half8 af[2][4], bf[2][4];

    // preload kstep 0 into buffer 0
#pragma unroll
    for (int i = 0; i < 4; ++i) {
        af[0][i] = *(const half8*)(ap[i]);
        bf[0][i] = *(const half8*)(bp[i]);
    }

    // 32 ksteps of K=32, unrolled by 2 with register ping-pong.
    // The kt==30 iteration prefetches k=1024 (64 elems past xh end) — this
    // lands in the bt region of d_ws (and bt's overrun lands in yh): safe,
    // values unused.
    for (int kt = 0; kt < 32; kt += 2) {
        const int ko1 = (kt + 1) * 32;
        const int ko2 = (kt + 2) * 32;
#pragma unroll
        for (int i = 0; i < 4; ++i) {
            af[1][i] = *(const half8*)(ap[i] + ko1);
            bf[1][i] = *(const half8*)(bp[i] + ko1);
        }
#pragma unroll
        for (int mi = 0; mi < 4; ++mi)
#pragma unroll
            for (int ni = 0; ni < 4; ++ni)
                acc[mi][ni] = __builtin_amdgcn_mfma_f32_16x16x32_f16(
                    af[0][mi], bf[0][ni], acc[mi][ni], 0, 0, 0);
#pragma unroll
        for (int i = 0; i < 4; ++i) {
            af[0][i] = *(const half8*)(ap[i] + ko2);
            bf[0][i] = *(const half8*)(bp[i] + ko2);
        }
#pragma unroll
        for (int mi = 0; mi < 4; ++mi)
#pragma unroll
            for (int ni = 0; ni < 4; ++ni)
                acc[mi][ni] = __builtin_amdgcn_mfma_f32_16x16x32_f16(
                    af[1][mi], bf[1][ni], acc[mi][ni], 0, 0, 0);
    }

    // Epilogue: C/D layout col = lane&15, row = (lane>>4)*4 + r (verified R1).
    // Gate is block-uniform: n-tile (128 wide) lies inside one 512-wide gate.
    const int gate = n0 >> 9;
    const float* bias = (gate == 0) ? zb : ((gate == 1) ? fb : ob);
    float bv[4];
#pragma unroll
    for (int ni = 0; ni < 4; ++ni)
        bv[ni] = bias[(n0 & 511) + wn + ni * 16 + l15];

#pragma unroll
    for (int mi = 0; mi < 4; ++mi) {
#pragma unroll
        for (int ni = 0; ni < 4; ++ni) {
#pragma unroll
            for (int r = 0; r < 4; ++r) {
                int m = m0 + wm + mi * 16 + q * 4 + r;
                int n = n0 + wn + ni * 16 + l15;
                float v = acc[mi][ni][r] + bv[ni];
                float a = (gate == 0) ? ftanh(v) : fsigmoid(v);
                yh[(long)m * Nn + n] = (_Float16)a;
            }
        }
    }
}

// ---- scan pass 1: per-chunk local scan over ACTIVATED z,f (h_in = 0) ----
// one wave per (batch, chunk); each lane owns 8 channels (half8 loads).
__global__ __launch_bounds__(64) void scan_partial(const _Float16* __restrict__ yh,
                                                   float* __restrict__ pf,
                                                   float* __restrict__ he) {
    int c = blockIdx.x & (NC - 1);
    int b = blockIdx.x >> 6;
    int lane = threadIdx.x;
    long base = ((long)(b * Tt + c * LC)) * Nn + lane * 8;
    float hl[8] = {0,0,0,0,0,0,0,0};
    float p[8]  = {1,1,1,1,1,1,1,1};
    for (int t = 0; t < LC; ++t) {
        half8 z8 = *(const half8*)&yh[base];
        half8 f8 = *(const half8*)&yh[base + 512];
#pragma unroll
        for (int j = 0; j < 8; ++j) {
            float f = (float)f8[j];
            hl[j] = f * hl[j] + (1.0f - f) * (float)z8[j];
            p[j] *= f;
        }
        base += Nn;
    }
    long o = ((long)(b * NC + c)) * Hh + lane * 8;
#pragma unroll
    for (int j = 0; j < 8; ++j) { pf[o + j] = p[j]; he[o + j] = hl[j]; }
}

// ---- scan pass 2: sequential combine over chunks -> h_in per chunk ----
__global__ __launch_bounds__(256) void scan_combine(const float* __restrict__ pf,
                                                    const float* __restrict__ he,
                                                    float* __restrict__ hin) {
    int idx = blockIdx.x * 256 + threadIdx.x; // b*512 + h, 4096 total
    int b = idx >> 9;
    int h = idx & 511;
    float hcur = 0.0f;
    for (int c = 0; c < NC; ++c) {
        int o = (b * NC + c) * Hh + h;
        hin[o] = hcur;
        hcur = pf[o] * hcur + he[o];
    }
}

// ---- scan pass 3: local scan with true h_in, apply o-gate, write out ----
__global__ __launch_bounds__(64) void scan_final(const _Float16* __restrict__ yh,
                                                 const float* __restrict__ hin,
                                                 float* __restrict__ out) {
    int c = blockIdx.x & (NC - 1);
    int b = blockIdx.x >> 6;
    int lane = threadIdx.x;
    long base  = ((long)(b * Tt + c * LC)) * Nn + lane * 8;
    long obase = ((long)(b * Tt + c * LC)) * Hh + lane * 8;
    long hb = ((long)(b * NC + c)) * Hh + lane * 8;
    float h[8];
#pragma unroll
    for (int j = 0; j < 8; ++j) h[j] = hin[hb + j];
    for (int t = 0; t < LC; ++t) {
        half8 z8 = *(const half8*)&yh[base];
        half8 f8 = *(const half8*)&yh[base + 512];
        half8 o8 = *(const half8*)&yh[base + 1024];
#pragma unroll
        for (int j = 0; j < 8; ++j) {
            float f = (float)f8[j];
            h[j] = f * h[j] + (1.0f - f) * (float)z8[j];
            out[obase + j] = h[j] * (float)o8[j];
        }
        base += Nn;
        obase += Hh;
    }
}

extern "C" void kernel_launch(void* const* d_in, const int* in_sizes, int n_in,
                              void* d_out, int out_size, void* d_ws, size_t ws_size,
                              hipStream_t stream) {
    const float* x  = (const float*)d_in[0];
    const float* zk = (const float*)d_in[1];
    const float* zbias = (const float*)d_in[2];
    const float* fk = (const float*)d_in[3];
    const float* fbias = (const float*)d_in[4];
    const float* ok = (const float*)d_in[5];
    const float* obias = (const float*)d_in[6];
    float* out = (float*)d_out;

    // Workspace layout (bytes) — identical footprint to round 1 (fits ws):
    char* ws = (char*)d_ws;
    _Float16* xh = (_Float16*)ws;                       // 8*2097664*2   = 33,562,624
    _Float16* bt = (_Float16*)(ws + 33562624);          // 1536*1024*2   =  3,145,728
    _Float16* yh = (_Float16*)(ws + 36708352);          // 32768*1536*2  = 100,663,296
    float*    pf = (float*)(ws + 137371648);            // 8*64*512*4    =  1,048,576
    float*    he = (float*)(ws + 138420224);            // 1,048,576
    float*    hin= (float*)(ws + 139468800);            // 1,048,576  (end 140,517,376)

    cvt_x<<<dim3((XBS/4 + 255) / 256, Bb), 256, 0, stream>>>(x, xh);
    cvt_w<<<dim3((Nn * Kk) / 256), 256, 0, stream>>>(zk, fk, ok, bt);
    gemm_qrnn<<<dim3(Mm / 128, Nn / 128), 256, 0, stream>>>(xh, bt, zbias, fbias, obias, yh);
    scan_partial<<<dim3(Bb * NC), 64, 0, stream>>>(yh, pf, he);
    scan_combine<<<dim3(16), 256, 0, stream>>>(pf, he, hin);
    scan_final<<<dim3(Bb * NC), 64, 0, stream>>>(yh, hin, out);
}

// Round 3
// 312.758 us; speedup vs baseline: 1.6980x; 1.6980x over previous
//
#include <hip/hip_runtime.h>
#include <hip/hip_fp16.h>
#include <stdint.h>

// Problem constants
#define Bb 8
#define Tt 4096
#define Cc 512
#define Hh 512
#define Mm (Bb*Tt)      // 32768
#define Nn (3*Hh)       // 1536
#define Kk (2*Cc)       // 1024
#define NC 64           // chunks per batch for the scan
#define LC (Tt/NC)      // 64 steps per chunk
#define XBS (Tt*Cc + Cc) // per-batch padded x stride (elems) = 2097664
#define BK 64

typedef _Float16 half8 __attribute__((ext_vector_type(8)));
typedef _Float16 half4 __attribute__((ext_vector_type(4)));
typedef float  floatx4 __attribute__((ext_vector_type(4)));

typedef const __attribute__((address_space(1))) uint32_t* gptr_t;
typedef __attribute__((address_space(3))) uint32_t* lptr_t;

__device__ __forceinline__ void g2lds16(const void* g, void* l) {
    __builtin_amdgcn_global_load_lds((gptr_t)g, (lptr_t)l, 16, 0, 0);
}

__device__ __forceinline__ float fsigmoid(float x) {
    return 1.0f / (1.0f + __expf(-x));
}
__device__ __forceinline__ float ftanh(float x) {
    return 2.0f / (1.0f + __expf(-2.0f * x)) - 1.0f;
}

// ---- x fp32 -> fp16 with 512-elem zero pad at front of each batch ----
__global__ __launch_bounds__(256) void cvt_x(const float* __restrict__ x,
                                             _Float16* __restrict__ xh) {
    long i4 = ((long)blockIdx.x * 256 + threadIdx.x) * 4;   // [0, XBS)
    int b = blockIdx.y;
    if (i4 >= XBS) return;
    half4 v;
    if (i4 >= Cc) {
        floatx4 xx = *(const floatx4*)&x[(long)b * (Tt*Cc) + i4 - Cc];
        v[0] = (_Float16)xx[0]; v[1] = (_Float16)xx[1];
        v[2] = (_Float16)xx[2]; v[3] = (_Float16)xx[3];
    } else {
        v[0] = v[1] = v[2] = v[3] = (_Float16)0.0f;
    }
    *(half4*)&xh[(long)b * XBS + i4] = v;
}

// ---- build Bt[n][kk] = kernel_{n/512}[kk/512][kk%512][n%512] as fp16 ----
__global__ __launch_bounds__(256) void cvt_w(const float* __restrict__ zk,
                                             const float* __restrict__ fk,
                                             const float* __restrict__ ok,
                                             _Float16* __restrict__ bt) {
    int idx = blockIdx.x * 256 + threadIdx.x; // < 1536*1024
    int n  = idx >> 10;
    int kk = idx & 1023;
    int which = n >> 9;
    int h = n & 511;
    int kw = kk >> 9;
    int c = kk & 511;
    const float* src = (which == 0) ? zk : ((which == 1) ? fk : ok);
    bt[idx] = (_Float16)src[kw * (Cc*Hh) + c * Hh + h];
}

// ---- MFMA fp16 GEMM with coalesced+swizzled LDS staging ----
// Y[m][n] = act_gate(A[m][:] @ Bt[n][:] + bias[n]) stored fp16.
// LDS tile: lX[row][p] (p = 16B kseg 0..7); slot (r,p) holds global kseg
// p ^ (r&7) of row r. Staging inst = 8 rows x 128B contiguous per row
// (8x128B coalesced transactions); ds_read phase-conflict-free (XOR swizzle).
__global__ __launch_bounds__(256, 3) void gemm_qrnn(const _Float16* __restrict__ xh,
                                                    const _Float16* __restrict__ bt,
                                                    const float* __restrict__ zb,
                                                    const float* __restrict__ fb,
                                                    const float* __restrict__ ob,
                                                    _Float16* __restrict__ yh) {
    __shared__ _Float16 lA[128 * BK];
    __shared__ _Float16 lB[128 * BK];

    const int tid  = threadIdx.x;
    const int lane = tid & 63;
    const int w    = tid >> 6;          // wave 0..3
    const int m0   = blockIdx.x * 128;
    const int n0   = blockIdx.y * 128;
    const int wm   = (w & 1) * 64;
    const int wn   = (w >> 1) * 64;
    const int q    = lane >> 4;
    const int l15  = lane & 15;

    // Staging lane decomposition: 8 rows x 8 ksegs per instruction.
    const int rl = lane >> 3;           // row within 8-row group
    const int j  = lane & 7;            // phys kseg (LDS slot order)
    const int jx = (j ^ rl) * 8;        // swizzled global k-elem offset

    const _Float16* asrc[4];
    const _Float16* bsrc[4];
    _Float16* adst[4];
    _Float16* bdst[4];
#pragma unroll
    for (int i = 0; i < 4; ++i) {
        int r0 = w * 32 + i * 8;
        int rgA = m0 + r0 + rl;
        asrc[i] = xh + (((long)(rgA + (rgA >> 12))) << 9) + jx;  // causal-pad row map
        int rgB = n0 + r0 + rl;
        bsrc[i] = bt + (((long)rgB) << 10) + jx;
        adst[i] = &lA[r0 * BK];
        bdst[i] = &lB[r0 * BK];
    }

    // ds_read addresses: row r = wX+mi*16+l15, phys kseg p0 = q ^ (l15&7)
    // (global kseg q, kstep 0); kstep 1 is p0^4 -> addr ^ 32 elems.
    int aaddr[4], baddr[4];
    const int psw = (q ^ (l15 & 7)) * 8;
#pragma unroll
    for (int i = 0; i < 4; ++i) {
        aaddr[i] = (wm + i * 16 + l15) * BK + psw;
        baddr[i] = (wn + i * 16 + l15) * BK + psw;
    }

    floatx4 acc[4][4] = {};

    for (int kt = 0; kt < Kk / BK; ++kt) {
        const int kb = kt * BK;
#pragma unroll
        for (int i = 0; i < 4; ++i) g2lds16(asrc[i] + kb, adst[i]);
#pragma unroll
        for (int i = 0; i < 4; ++i) g2lds16(bsrc[i] + kb, bdst[i]);
        __syncthreads();

        half8 a0[4], a1[4], b0[4], b1[4];
#pragma unroll
        for (int i = 0; i < 4; ++i) {
            a0[i] = *(const half8*)&lA[aaddr[i]];
            a1[i] = *(const half8*)&lA[aaddr[i] ^ 32];
            b0[i] = *(const half8*)&lB[baddr[i]];
            b1[i] = *(const half8*)&lB[baddr[i] ^ 32];
        }
#pragma unroll
        for (int mi = 0; mi < 4; ++mi)
#pragma unroll
            for (int ni = 0; ni < 4; ++ni)
                acc[mi][ni] = __builtin_amdgcn_mfma_f32_16x16x32_f16(
                    a0[mi], b0[ni], acc[mi][ni], 0, 0, 0);
#pragma unroll
        for (int mi = 0; mi < 4; ++mi)
#pragma unroll
            for (int ni = 0; ni < 4; ++ni)
                acc[mi][ni] = __builtin_amdgcn_mfma_f32_16x16x32_f16(
                    a1[mi], b1[ni], acc[mi][ni], 0, 0, 0);
        __syncthreads();
    }

    // Epilogue: C/D layout col = lane&15, row = (lane>>4)*4 + r (verified).
    // Gate block-uniform (n-tile inside one 512-wide gate). Fused bias+act.
    const int gate = n0 >> 9;
    const float* bias = (gate == 0) ? zb : ((gate == 1) ? fb : ob);
    float bv[4];
#pragma unroll
    for (int ni = 0; ni < 4; ++ni)
        bv[ni] = bias[(n0 & 511) + wn + ni * 16 + l15];

#pragma unroll
    for (int mi = 0; mi < 4; ++mi) {
#pragma unroll
        for (int ni = 0; ni < 4; ++ni) {
#pragma unroll
            for (int r = 0; r < 4; ++r) {
                int m = m0 + wm + mi * 16 + q * 4 + r;
                int n = n0 + wn + ni * 16 + l15;
                float v = acc[mi][ni][r] + bv[ni];
                float a = (gate == 0) ? ftanh(v) : fsigmoid(v);
                yh[(long)m * Nn + n] = (_Float16)a;
            }
        }
    }
}

// ---- scan pass 1: per-chunk local scan over ACTIVATED z,f (h_in = 0) ----
__global__ __launch_bounds__(64) void scan_partial(const _Float16* __restrict__ yh,
                                                   float* __restrict__ pf,
                                                   float* __restrict__ he) {
    int c = blockIdx.x & (NC - 1);
    int b = blockIdx.x >> 6;
    int lane = threadIdx.x;
    long base = ((long)(b * Tt + c * LC)) * Nn + lane * 8;
    float hl[8] = {0,0,0,0,0,0,0,0};
    float p[8]  = {1,1,1,1,1,1,1,1};
#pragma unroll 8
    for (int t = 0; t < LC; ++t) {
        half8 z8 = *(const half8*)&yh[base];
        half8 f8 = *(const half8*)&yh[base + 512];
#pragma unroll
        for (int jj = 0; jj < 8; ++jj) {
            float f = (float)f8[jj];
            hl[jj] = f * hl[jj] + (1.0f - f) * (float)z8[jj];
            p[jj] *= f;
        }
        base += Nn;
    }
    long o = ((long)(b * NC + c)) * Hh + lane * 8;
#pragma unroll
    for (int jj = 0; jj < 8; ++jj) { pf[o + jj] = p[jj]; he[o + jj] = hl[jj]; }
}

// ---- scan pass 2: sequential combine over chunks -> h_in per chunk ----
__global__ __launch_bounds__(256) void scan_combine(const float* __restrict__ pf,
                                                    const float* __restrict__ he,
                                                    float* __restrict__ hin) {
    int idx = blockIdx.x * 256 + threadIdx.x; // b*512 + h, 4096 total
    int b = idx >> 9;
    int h = idx & 511;
    float hcur = 0.0f;
#pragma unroll 4
    for (int c = 0; c < NC; ++c) {
        int o = (b * NC + c) * Hh + h;
        hin[o] = hcur;
        hcur = pf[o] * hcur + he[o];
    }
}

// ---- scan pass 3: local scan with true h_in, apply o-gate, write out ----
__global__ __launch_bounds__(64) void scan_final(const _Float16* __restrict__ yh,
                                                 const float* __restrict__ hin,
                                                 float* __restrict__ out) {
    int c = blockIdx.x & (NC - 1);
    int b = blockIdx.x >> 6;
    int lane = threadIdx.x;
    long base  = ((long)(b * Tt + c * LC)) * Nn + lane * 8;
    long obase = ((long)(b * Tt + c * LC)) * Hh + lane * 8;
    long hb = ((long)(b * NC + c)) * Hh + lane * 8;
    float h[8];
#pragma unroll
    for (int jj = 0; jj < 8; ++jj) h[jj] = hin[hb + jj];
#pragma unroll 4
    for (int t = 0; t < LC; ++t) {
        half8 z8 = *(const half8*)&yh[base];
        half8 f8 = *(const half8*)&yh[base + 512];
        half8 o8 = *(const half8*)&yh[base + 1024];
#pragma unroll
        for (int jj = 0; jj < 8; ++jj) {
            float f = (float)f8[jj];
            h[jj] = f * h[jj] + (1.0f - f) * (float)z8[jj];
            out[obase + jj] = h[jj] * (float)o8[jj];
        }
        base += Nn;
        obase += Hh;
    }
}

extern "C" void kernel_launch(void* const* d_in, const int* in_sizes, int n_in,
                              void* d_out, int out_size, void* d_ws, size_t ws_size,
                              hipStream_t stream) {
    const float* x  = (const float*)d_in[0];
    const float* zk = (const float*)d_in[1];
    const float* zbias = (const float*)d_in[2];
    const float* fk = (const float*)d_in[3];
    const float* fbias = (const float*)d_in[4];
    const float* ok = (const float*)d_in[5];
    const float* obias = (const float*)d_in[6];
    float* out = (float*)d_out;

    // Workspace layout (bytes) — identical footprint to round 1 (fits ws):
    char* ws = (char*)d_ws;
    _Float16* xh = (_Float16*)ws;                       // 8*2097664*2   = 33,562,624
    _Float16* bt = (_Float16*)(ws + 33562624);          // 1536*1024*2   =  3,145,728
    _Float16* yh = (_Float16*)(ws + 36708352);          // 32768*1536*2  = 100,663,296
    float*    pf = (float*)(ws + 137371648);            // 8*64*512*4    =  1,048,576
    float*    he = (float*)(ws + 138420224);            // 1,048,576
    float*    hin= (float*)(ws + 139468800);            // 1,048,576  (end 140,517,376)

    cvt_x<<<dim3((XBS/4 + 255) / 256, Bb), 256, 0, stream>>>(x, xh);
    cvt_w<<<dim3((Nn * Kk) / 256), 256, 0, stream>>>(zk, fk, ok, bt);
    gemm_qrnn<<<dim3(Mm / 128, Nn / 128), 256, 0, stream>>>(xh, bt, zbias, fbias, obias, yh);
    scan_partial<<<dim3(Bb * NC), 64, 0, stream>>>(yh, pf, he);
    scan_combine<<<dim3(16), 256, 0, stream>>>(pf, he, hin);
    scan_final<<<dim3(Bb * NC), 64, 0, stream>>>(yh, hin, out);
}

// Round 4
// 304.413 us; speedup vs baseline: 1.7446x; 1.0274x over previous
//
#include <hip/hip_runtime.h>
#include <hip/hip_fp16.h>
#include <stdint.h>

// Problem constants
#define Bb 8
#define Tt 4096
#define Cc 512
#define Hh 512
#define Mm (Bb*Tt)      // 32768
#define Nn (3*Hh)       // 1536
#define Kk (2*Cc)       // 1024
#define NC 256          // chunks per batch for the scan
#define LC (Tt/NC)      // 16 steps per chunk
#define XBS (Tt*Cc + Cc) // per-batch padded x stride (elems) = 2097664
#define BK 64

typedef _Float16 half8 __attribute__((ext_vector_type(8)));
typedef _Float16 half4 __attribute__((ext_vector_type(4)));
typedef float  floatx4 __attribute__((ext_vector_type(4)));

typedef const __attribute__((address_space(1))) uint32_t* gptr_t;
typedef __attribute__((address_space(3))) uint32_t* lptr_t;

__device__ __forceinline__ void g2lds16(const void* g, void* l) {
    __builtin_amdgcn_global_load_lds((gptr_t)g, (lptr_t)l, 16, 0, 0);
}

__device__ __forceinline__ float fsigmoid(float x) {
    return 1.0f / (1.0f + __expf(-x));
}
__device__ __forceinline__ float ftanh(float x) {
    return 2.0f / (1.0f + __expf(-2.0f * x)) - 1.0f;
}

// ---- x fp32 -> fp16 with 512-elem zero pad at front of each batch ----
__global__ __launch_bounds__(256) void cvt_x(const float* __restrict__ x,
                                             _Float16* __restrict__ xh) {
    long i4 = ((long)blockIdx.x * 256 + threadIdx.x) * 4;   // [0, XBS)
    int b = blockIdx.y;
    if (i4 >= XBS) return;
    half4 v;
    if (i4 >= Cc) {
        floatx4 xx = *(const floatx4*)&x[(long)b * (Tt*Cc) + i4 - Cc];
        v[0] = (_Float16)xx[0]; v[1] = (_Float16)xx[1];
        v[2] = (_Float16)xx[2]; v[3] = (_Float16)xx[3];
    } else {
        v[0] = v[1] = v[2] = v[3] = (_Float16)0.0f;
    }
    *(half4*)&xh[(long)b * XBS + i4] = v;
}

// ---- build Bt[n][kk] via LDS-tiled transpose (both sides coalesced) ----
// Bt[n=which*512+h][kk=kw*512+c] = src_which[kw][c][h]
__global__ __launch_bounds__(256) void cvt_w(const float* __restrict__ zk,
                                             const float* __restrict__ fk,
                                             const float* __restrict__ ok,
                                             _Float16* __restrict__ bt) {
    __shared__ float tile[64][65];
    const int c0 = (blockIdx.x & 7) * 64;
    const int h0 = (blockIdx.x >> 3) * 64;
    const int which = blockIdx.y >> 1;
    const int kw    = blockIdx.y & 1;
    const float* src = (which == 0) ? zk : ((which == 1) ? fk : ok);
    src += kw * (Cc * Hh);
    const int tr  = threadIdx.x >> 4;        // 0..15
    const int tc4 = (threadIdx.x & 15) * 4;  // 0..60
#pragma unroll
    for (int i = 0; i < 4; ++i) {
        int c = tr + i * 16;
        floatx4 v = *(const floatx4*)&src[(long)(c0 + c) * Hh + h0 + tc4];
        tile[c][tc4 + 0] = v[0]; tile[c][tc4 + 1] = v[1];
        tile[c][tc4 + 2] = v[2]; tile[c][tc4 + 3] = v[3];
    }
    __syncthreads();
#pragma unroll
    for (int i = 0; i < 4; ++i) {
        int h = tr + i * 16;
        half4 o;
#pragma unroll
        for (int j = 0; j < 4; ++j) o[j] = (_Float16)tile[tc4 + j][h];
        *(half4*)&bt[((long)(which * 512 + h0 + h) << 10) + kw * 512 + c0 + tc4] = o;
    }
}

// ---- MFMA fp16 GEMM with coalesced+swizzled LDS staging (R3, unchanged) ----
__global__ __launch_bounds__(256, 3) void gemm_qrnn(const _Float16* __restrict__ xh,
                                                    const _Float16* __restrict__ bt,
                                                    const float* __restrict__ zb,
                                                    const float* __restrict__ fb,
                                                    const float* __restrict__ ob,
                                                    _Float16* __restrict__ yh) {
    __shared__ _Float16 lA[128 * BK];
    __shared__ _Float16 lB[128 * BK];

    const int tid  = threadIdx.x;
    const int lane = tid & 63;
    const int w    = tid >> 6;
    const int m0   = blockIdx.x * 128;
    const int n0   = blockIdx.y * 128;
    const int wm   = (w & 1) * 64;
    const int wn   = (w >> 1) * 64;
    const int q    = lane >> 4;
    const int l15  = lane & 15;

    const int rl = lane >> 3;
    const int j  = lane & 7;
    const int jx = (j ^ rl) * 8;

    const _Float16* asrc[4];
    const _Float16* bsrc[4];
    _Float16* adst[4];
    _Float16* bdst[4];
#pragma unroll
    for (int i = 0; i < 4; ++i) {
        int r0 = w * 32 + i * 8;
        int rgA = m0 + r0 + rl;
        asrc[i] = xh + (((long)(rgA + (rgA >> 12))) << 9) + jx;
        int rgB = n0 + r0 + rl;
        bsrc[i] = bt + (((long)rgB) << 10) + jx;
        adst[i] = &lA[r0 * BK];
        bdst[i] = &lB[r0 * BK];
    }

    int aaddr[4], baddr[4];
    const int psw = (q ^ (l15 & 7)) * 8;
#pragma unroll
    for (int i = 0; i < 4; ++i) {
        aaddr[i] = (wm + i * 16 + l15) * BK + psw;
        baddr[i] = (wn + i * 16 + l15) * BK + psw;
    }

    floatx4 acc[4][4] = {};

    for (int kt = 0; kt < Kk / BK; ++kt) {
        const int kb = kt * BK;
#pragma unroll
        for (int i = 0; i < 4; ++i) g2lds16(asrc[i] + kb, adst[i]);
#pragma unroll
        for (int i = 0; i < 4; ++i) g2lds16(bsrc[i] + kb, bdst[i]);
        __syncthreads();

        half8 a0[4], a1[4], b0[4], b1[4];
#pragma unroll
        for (int i = 0; i < 4; ++i) {
            a0[i] = *(const half8*)&lA[aaddr[i]];
            a1[i] = *(const half8*)&lA[aaddr[i] ^ 32];
            b0[i] = *(const half8*)&lB[baddr[i]];
            b1[i] = *(const half8*)&lB[baddr[i] ^ 32];
        }
#pragma unroll
        for (int mi = 0; mi < 4; ++mi)
#pragma unroll
            for (int ni = 0; ni < 4; ++ni)
                acc[mi][ni] = __builtin_amdgcn_mfma_f32_16x16x32_f16(
                    a0[mi], b0[ni], acc[mi][ni], 0, 0, 0);
#pragma unroll
        for (int mi = 0; mi < 4; ++mi)
#pragma unroll
            for (int ni = 0; ni < 4; ++ni)
                acc[mi][ni] = __builtin_amdgcn_mfma_f32_16x16x32_f16(
                    a1[mi], b1[ni], acc[mi][ni], 0, 0, 0);
        __syncthreads();
    }

    const int gate = n0 >> 9;
    const float* bias = (gate == 0) ? zb : ((gate == 1) ? fb : ob);
    float bv[4];
#pragma unroll
    for (int ni = 0; ni < 4; ++ni)
        bv[ni] = bias[(n0 & 511) + wn + ni * 16 + l15];

#pragma unroll
    for (int mi = 0; mi < 4; ++mi) {
#pragma unroll
        for (int ni = 0; ni < 4; ++ni) {
#pragma unroll
            for (int r = 0; r < 4; ++r) {
                int m = m0 + wm + mi * 16 + q * 4 + r;
                int n = n0 + wn + ni * 16 + l15;
                float v = acc[mi][ni][r] + bv[ni];
                float a = (gate == 0) ? ftanh(v) : fsigmoid(v);
                yh[(long)m * Nn + n] = (_Float16)a;
            }
        }
    }
}

// ---- scan pass 1: per-chunk local scan over ACTIVATED z,f (h_in = 0) ----
// one wave per (batch, chunk); each lane owns 8 channels (half8 loads).
__global__ __launch_bounds__(64) void scan_partial(const _Float16* __restrict__ yh,
                                                   float* __restrict__ pf,
                                                   float* __restrict__ he) {
    int c = blockIdx.x & (NC - 1);
    int b = blockIdx.x >> 8;
    int lane = threadIdx.x;
    long base = ((long)(b * Tt + c * LC)) * Nn + lane * 8;
    float hl[8] = {0,0,0,0,0,0,0,0};
    float p[8]  = {1,1,1,1,1,1,1,1};
#pragma unroll 4
    for (int t = 0; t < LC; ++t) {
        half8 z8 = *(const half8*)&yh[base];
        half8 f8 = *(const half8*)&yh[base + 512];
#pragma unroll
        for (int jj = 0; jj < 8; ++jj) {
            float f = (float)f8[jj];
            hl[jj] = f * hl[jj] + (1.0f - f) * (float)z8[jj];
            p[jj] *= f;
        }
        base += Nn;
    }
    long o = ((long)(b * NC + c)) * Hh + lane * 8;
#pragma unroll
    for (int jj = 0; jj < 8; ++jj) { pf[o + jj] = p[jj]; he[o + jj] = hl[jj]; }
}

// ---- scan pass 2: sequential combine over chunks -> h_in per chunk ----
__global__ __launch_bounds__(256) void scan_combine(const float* __restrict__ pf,
                                                    const float* __restrict__ he,
                                                    float* __restrict__ hin) {
    int idx = blockIdx.x * 256 + threadIdx.x; // b*512 + h, 4096 total
    int b = idx >> 9;
    int h = idx & 511;
    float hcur = 0.0f;
#pragma unroll 8
    for (int c = 0; c < NC; ++c) {
        int o = (b * NC + c) * Hh + h;
        hin[o] = hcur;
        hcur = pf[o] * hcur + he[o];
    }
}

// ---- scan pass 3: local scan with true h_in, apply o-gate, write out ----
__global__ __launch_bounds__(64) void scan_final(const _Float16* __restrict__ yh,
                                                 const float* __restrict__ hin,
                                                 float* __restrict__ out) {
    int c = blockIdx.x & (NC - 1);
    int b = blockIdx.x >> 8;
    int lane = threadIdx.x;
    long base  = ((long)(b * Tt + c * LC)) * Nn + lane * 8;
    long obase = ((long)(b * Tt + c * LC)) * Hh + lane * 8;
    long hb = ((long)(b * NC + c)) * Hh + lane * 8;
    float h[8];
#pragma unroll
    for (int jj = 0; jj < 8; ++jj) h[jj] = hin[hb + jj];
#pragma unroll 4
    for (int t = 0; t < LC; ++t) {
        half8 z8 = *(const half8*)&yh[base];
        half8 f8 = *(const half8*)&yh[base + 512];
        half8 o8 = *(const half8*)&yh[base + 1024];
#pragma unroll
        for (int jj = 0; jj < 8; ++jj) {
            float f = (float)f8[jj];
            h[jj] = f * h[jj] + (1.0f - f) * (float)z8[jj];
            out[obase + jj] = h[jj] * (float)o8[jj];
        }
        base += Nn;
        obase += Hh;
    }
}

extern "C" void kernel_launch(void* const* d_in, const int* in_sizes, int n_in,
                              void* d_out, int out_size, void* d_ws, size_t ws_size,
                              hipStream_t stream) {
    const float* x  = (const float*)d_in[0];
    const float* zk = (const float*)d_in[1];
    const float* zbias = (const float*)d_in[2];
    const float* fk = (const float*)d_in[3];
    const float* fbias = (const float*)d_in[4];
    const float* ok = (const float*)d_in[5];
    const float* obias = (const float*)d_in[6];
    float* out = (float*)d_out;

    // Workspace layout (bytes):
    //   xh 33,562,624 | bt 3,145,728 | yh 100,663,296   (total 137,371,648)
    // pf/he/hin (4 MB each) OVERLAY the xh region — xh is dead after
    // gemm_qrnn; stream order (gemm -> partial -> combine -> final) makes
    // the reuse safe.
    char* ws = (char*)d_ws;
    _Float16* xh = (_Float16*)ws;
    _Float16* bt = (_Float16*)(ws + 33562624);
    _Float16* yh = (_Float16*)(ws + 36708352);
    float*    pf = (float*)(ws);                 // 8*256*512*4 = 4,194,304
    float*    he = (float*)(ws + 4194304);       // 4,194,304
    float*    hin= (float*)(ws + 8388608);       // 4,194,304 (ends 12.6 MB < 33.5 MB)

    cvt_x<<<dim3((XBS/4 + 255) / 256, Bb), 256, 0, stream>>>(x, xh);
    cvt_w<<<dim3(64, 6), 256, 0, stream>>>(zk, fk, ok, bt);
    gemm_qrnn<<<dim3(Mm / 128, Nn / 128), 256, 0, stream>>>(xh, bt, zbias, fbias, obias, yh);
    scan_partial<<<dim3(Bb * NC), 64, 0, stream>>>(yh, pf, he);
    scan_combine<<<dim3(16), 256, 0, stream>>>(pf, he, hin);
    scan_final<<<dim3(Bb * NC), 64, 0, stream>>>(yh, hin, out);
}